// Round 22
// baseline (139.830 us; speedup 1.0000x reference)
//
#include <hip/hip_runtime.h>
#include <cstdio>
#include <cstdint>

// Problem constants
#define BATCH 8
#define CH    512
#define OC3   1536      // 3*CH
#define NPIX  4096      // 64*64
#define HEADS 8
#define HDIM  64
#define KDEPTH 512
#define SCALE 0.125f    // 64^-0.5
#define NSPLIT 32       // S-partials per (b,h): one per 128-n window

typedef __bf16 bf16;
typedef __bf16 bf16x4 __attribute__((ext_vector_type(4)));
typedef __bf16 bf16x8 __attribute__((ext_vector_type(8)));
typedef float  f32x4  __attribute__((ext_vector_type(4)));

#define AS1 __attribute__((address_space(1)))
#define AS3 __attribute__((address_space(3)))

#define NCONV ((OC3 * KDEPTH) / 256)   // 3072 convert blocks
#define NWVT  64                       // wvt tiles
#define NTRP  (64 * 8 * BATCH)         // 4096 transpose tiles

// ---------------------------------------------------------------------------
// Merged prep: [0,3072) flat convert qkv_w->bf16; [3072,3136) Wv^T tiles;
// [3136,7232) x -> xt transpose tiles.
// ---------------------------------------------------------------------------
__global__ __launch_bounds__(256) void prep_kernel(
    const float* __restrict__ qkv_w, const float* __restrict__ x,
    bf16* __restrict__ wq_b, bf16* __restrict__ wvt, bf16* __restrict__ xt)
{
    const int bid = blockIdx.x;
    const int t = threadIdx.x;
    __shared__ float shbuf[64 * 68];

    if (bid < NCONV) {
        const int i = bid * 256 + t;
        wq_b[i] = (bf16)qkv_w[i];
        return;
    }
    if (bid < NCONV + NWVT) {
        const int tb = bid - NCONV;
        const int c0 = (tb & 7) * 64;
        const int d0 = (tb >> 3) * 64;
        const float* wv = qkv_w + (size_t)2 * CH * KDEPTH;
        #pragma unroll
        for (int i = 0; i < 4; ++i) {
            const int lin = t + 256 * i;
            const int row = lin >> 4;
            const int c4  = (lin & 15) * 4;
            const float4 v = *(const float4*)(wv + (size_t)(d0 + row) * CH + c0 + c4);
            shbuf[row * 68 + c4 + 0] = v.x; shbuf[row * 68 + c4 + 1] = v.y;
            shbuf[row * 68 + c4 + 2] = v.z; shbuf[row * 68 + c4 + 3] = v.w;
        }
        __syncthreads();
        #pragma unroll
        for (int i = 0; i < 2; ++i) {
            const int lin  = t + 256 * i;
            const int crow = lin >> 3;
            const int d8   = (lin & 7) * 8;
            bf16x8 v;
            #pragma unroll
            for (int j = 0; j < 8; ++j) v[j] = (bf16)shbuf[(d8 + j) * 68 + crow];
            *(bf16x8*)(wvt + (size_t)(c0 + crow) * CH + d0 + d8) = v;
        }
        return;
    }
    {
        const int tid = bid - NCONV - NWVT;       // 0..4095
        const int b  = tid >> 9;
        const int rem = tid & 511;
        const int n0 = (rem & 63) * 64;
        const int c0 = (rem >> 6) * 64;
        const float* xp = x + (size_t)b * CH * NPIX;

        #pragma unroll
        for (int i = 0; i < 4; ++i) {
            const int lin = t + 256 * i;
            const int r   = lin >> 4;
            const int c4  = (lin & 15) * 4;
            const float4 v = *(const float4*)(xp + (size_t)(c0 + r) * 4096 + n0 + c4);
            shbuf[r * 65 + c4 + 0] = v.x; shbuf[r * 65 + c4 + 1] = v.y;
            shbuf[r * 65 + c4 + 2] = v.z; shbuf[r * 65 + c4 + 3] = v.w;
        }
        __syncthreads();

        bf16* op = xt + (size_t)b * NPIX * CH;
        #pragma unroll
        for (int i = 0; i < 2; ++i) {
            const int lin = t + 256 * i;
            const int n   = lin >> 3;
            const int c8  = (lin & 7) * 8;
            bf16x8 v;
            #pragma unroll
            for (int jj = 0; jj < 8; ++jj) v[jj] = (bf16)shbuf[(c8 + jj) * 65 + n];
            *(bf16x8*)(op + (size_t)(n0 + n) * CH + c0 + c8) = v;
        }
    }
}

// ---------------------------------------------------------------------------
// Fused Q/K GEMM + QK^T partial (R18-proven). Block (nwin=bx, head=by, b).
// ---------------------------------------------------------------------------
__global__ __launch_bounds__(256) void gemm_qks_kernel(
    const bf16* __restrict__ A, const bf16* __restrict__ Bt,
    const float* __restrict__ qkv_b, bf16* __restrict__ part)
{
    const int nwg  = gridDim.x * gridDim.y;          // 256
    const int orig = blockIdx.x + gridDim.x * blockIdx.y;
    const int wg   = (orig & 7) * (nwg >> 3) + (orig >> 3);
    const int head = wg % gridDim.y;
    const int bx   = wg / gridDim.y;

    const int b  = blockIdx.z;
    const int n0 = bx * 128;
    const bf16* Bp = Bt + (size_t)b * NPIX * KDEPTH;

    __shared__ bf16 smem[3 * 8192];

    const int t    = threadIdx.x;
    const int lane = t & 63;
    const int wave = t >> 6;
    const int wr   = wave >> 1, wc = wave & 1;

    f32x4 acc[4][4];
    const f32x4 zf = {0.f, 0.f, 0.f, 0.f};
    #pragma unroll
    for (int i = 0; i < 4; ++i)
        #pragma unroll
        for (int j = 0; j < 4; ++j) acc[i][j] = zf;

    auto STAGE = [&](int tile) {
        bf16* buf = smem + (tile % 3) * 8192;
        const int k0 = tile * 32;
        #pragma unroll
        for (int i = 0; i < 2; ++i) {
            const int c   = t + 256 * i;
            const int lr  = c >> 2;
            const int kb  = ((c & 3) ^ ((lr >> 1) & 3)) * 8;
            const int src = (lr < 64) ? (head * HDIM + lr)
                                      : (CH + head * HDIM + (lr - 64));
            __builtin_amdgcn_global_load_lds(
                (const AS1 void*)(A + (size_t)src * KDEPTH + k0 + kb),
                (AS3 void*)(buf + c * 8), 16, 0, 0);
            __builtin_amdgcn_global_load_lds(
                (const AS1 void*)(Bp + (size_t)(n0 + lr) * KDEPTH + k0 + kb),
                (AS3 void*)(buf + 4096 + c * 8), 16, 0, 0);
        }
    };

    auto COMPUTE = [&](int bufi) {
        const bf16* AsP = smem + bufi * 8192;
        const bf16* BsP = AsP + 4096;
        bf16x8 af[4], bfv[4];
        #pragma unroll
        for (int i = 0; i < 4; ++i) {
            const int ar = wr * 64 + i * 16 + (lane & 15);
            const int ja = (lane >> 4) ^ ((ar >> 1) & 3);
            af[i]  = *(const bf16x8*)(AsP + ar * 32 + ja * 8);
            const int br = wc * 64 + i * 16 + (lane & 15);
            const int jb = (lane >> 4) ^ ((br >> 1) & 3);
            bfv[i] = *(const bf16x8*)(BsP + br * 32 + jb * 8);
        }
        __builtin_amdgcn_s_setprio(1);
        #pragma unroll
        for (int i = 0; i < 4; ++i)
            #pragma unroll
            for (int j = 0; j < 4; ++j)
                acc[i][j] = __builtin_amdgcn_mfma_f32_16x16x32_bf16(
                    af[i], bfv[j], acc[i][j], 0, 0, 0);
        __builtin_amdgcn_s_setprio(0);
    };

    STAGE(0); STAGE(1);
    asm volatile("s_waitcnt vmcnt(4)" ::: "memory");
    asm volatile("s_barrier" ::: "memory");

    int cur = 0;
    for (int kt = 0; kt < 14; ++kt) {
        STAGE(kt + 2);
        COMPUTE(cur);
        __builtin_amdgcn_sched_barrier(0);
        asm volatile("s_waitcnt vmcnt(4)" ::: "memory");
        asm volatile("s_barrier" ::: "memory");
        cur = (cur + 1) % 3;
    }
    COMPUTE(cur);
    __builtin_amdgcn_sched_barrier(0);
    asm volatile("s_waitcnt vmcnt(0)" ::: "memory");
    asm volatile("s_barrier" ::: "memory");
    cur = (cur + 1) % 3;
    COMPUTE(cur);
    __syncthreads();

    // Bounce: acc (+bias) -> ct[128][128] bf16, chunk-slot ^ (row&15)
    bf16* ct = smem;
    #pragma unroll
    for (int i = 0; i < 4; ++i) {
        const int mlb = wr * 64 + i * 16 + (lane >> 4) * 4;
        #pragma unroll
        for (int r = 0; r < 4; ++r) {
            const int row = mlb + r;
            const int bsrc = (row < 64) ? (head * HDIM + row)
                                        : (CH + head * HDIM + (row - 64));
            const float bv = qkv_b[bsrc];
            #pragma unroll
            for (int j = 0; j < 4; ++j) {
                const int n = wc * 64 + j * 16 + (lane & 15);
                ct[row * 128 + (((n >> 3) ^ (row & 15)) * 8) + (n & 7)] =
                    (bf16)(acc[i][j][r] + bv);
            }
        }
    }
    __syncthreads();

    // S-partial: wave w -> e-range w*16..+16. 4 ksteps of 32 n.
    f32x4 sacc[4];
    #pragma unroll
    for (int df = 0; df < 4; ++df) sacc[df] = zf;
    #pragma unroll
    for (int ks = 0; ks < 4; ++ks) {
        const int slot8 = ((ks * 4 + (lane >> 4)) ^ (lane & 15)) * 8;
        const bf16x8 kf = *(const bf16x8*)(ct + (64 + wave * 16 + (lane & 15)) * 128 + slot8);
        #pragma unroll
        for (int df = 0; df < 4; ++df) {
            const bf16x8 qf = *(const bf16x8*)(ct + (df * 16 + (lane & 15)) * 128 + slot8);
            sacc[df] = __builtin_amdgcn_mfma_f32_16x16x32_bf16(qf, kf, sacc[df], 0, 0, 0);
        }
    }

    bf16* pp = part + (((size_t)(b * 8 + head) * NSPLIT + bx) * 64) * 64;
    #pragma unroll
    for (int df = 0; df < 4; ++df)
        #pragma unroll
        for (int r = 0; r < 4; ++r)
            pp[(size_t)(df * 16 + (lane >> 4) * 4 + r) * 64 + wave * 16 + (lane & 15)]
                = (bf16)sacc[df][r];
}

// ---------------------------------------------------------------------------
// Reduce 32 bf16 partials + row softmax for ALL 8 heads + head-mean.
// grid (8, BATCH). Block (rg, b): rows rg*8..+8; 32 thr/row, paired e.
// ---------------------------------------------------------------------------
__global__ __launch_bounds__(256) void qk_reduce_softmax_mean_kernel(
    const bf16* __restrict__ part, float* __restrict__ attn,
    float* __restrict__ attn_mean)
{
    const int rg = blockIdx.x, b = blockIdx.y;
    const int t  = threadIdx.x;
    const int row = rg * 8 + (t >> 5);
    const int le  = t & 31;

    float m0acc = 0.f, m1acc = 0.f;
    #pragma unroll
    for (int h = 0; h < 8; ++h) {
        const bf16* pb = part + (size_t)(b * 8 + h) * NSPLIT * 4096 + row * 64 + 2 * le;
        float v0 = 0.f, v1 = 0.f;
        #pragma unroll 8
        for (int s = 0; s < NSPLIT; ++s) {
            v0 += (float)pb[(size_t)s * 4096];
            v1 += (float)pb[(size_t)s * 4096 + 1];
        }

        float m = fmaxf(v0, v1);
        m = fmaxf(m, __shfl_xor(m, 1));
        m = fmaxf(m, __shfl_xor(m, 2));
        m = fmaxf(m, __shfl_xor(m, 4));
        m = fmaxf(m, __shfl_xor(m, 8));
        m = fmaxf(m, __shfl_xor(m, 16));

        v0 = __expf((v0 - m) * SCALE);
        v1 = __expf((v1 - m) * SCALE);
        float sum = v0 + v1;
        sum += __shfl_xor(sum, 1);
        sum += __shfl_xor(sum, 2);
        sum += __shfl_xor(sum, 4);
        sum += __shfl_xor(sum, 8);
        sum += __shfl_xor(sum, 16);
        const float inv = 1.f / sum;

        const float p0 = v0 * inv, p1 = v1 * inv;
        float* arow = attn + (((size_t)(b * 8 + h) * 64) + row) * 64;
        float2 o; o.x = p0; o.y = p1;
        *(float2*)(arow + 2 * le) = o;
        m0acc += p0; m1acc += p1;
    }

    float2 om; om.x = m0acc * 0.125f; om.y = m1acc * 0.125f;
    *(float2*)(attn_mean + ((size_t)b * 64 + row) * 64 + 2 * le) = om;
}

// ---------------------------------------------------------------------------
// W'[b][o][h*64+e] = sum_d proj_w[o][h*64+d]*attn[b,h,d,e] (fp32->bf16), AND
// bias2p[b][h][o] = sum_e W'[o][h*64+e]*bv[h*64+e]  (deterministic in-wave).
// ---------------------------------------------------------------------------
__global__ __launch_bounds__(256) void wprime_kernel(
    const float* __restrict__ proj_w, const float* __restrict__ attn,
    const float* __restrict__ bv, bf16* __restrict__ wp,
    float* __restrict__ bias2p)
{
    const int o0 = blockIdx.x * 64;
    const int h  = blockIdx.y;
    const int b  = blockIdx.z;

    __shared__ float ws[64][65];
    __shared__ float as_[64][65];

    const int t = threadIdx.x;
    #pragma unroll
    for (int i = 0; i < 4; ++i) {
        const int lin = t + 256 * i;
        const int r   = lin >> 4;
        const int c4  = (lin & 15) * 4;
        const float4 wv = *(const float4*)(proj_w + (size_t)(o0 + r) * CH + h * HDIM + c4);
        ws[r][c4 + 0] = wv.x; ws[r][c4 + 1] = wv.y;
        ws[r][c4 + 2] = wv.z; ws[r][c4 + 3] = wv.w;
        const float4 av = *(const float4*)(attn + (((size_t)(b * 8 + h) * 64) + r) * 64 + c4);
        as_[r][c4 + 0] = av.x; as_[r][c4 + 1] = av.y;
        as_[r][c4 + 2] = av.z; as_[r][c4 + 3] = av.w;
    }
    __syncthreads();

    const int tx = t & 15, ty = t >> 4;
    const int to = ty * 4, te = tx * 4;
    float acc[4][4] = {};
    for (int d = 0; d < 64; ++d) {
        float a[4], bb[4];
        #pragma unroll
        for (int i = 0; i < 4; ++i) a[i]  = ws[to + i][d];
        #pragma unroll
        for (int j = 0; j < 4; ++j) bb[j] = as_[d][te + j];
        #pragma unroll
        for (int i = 0; i < 4; ++i)
            #pragma unroll
            for (int j = 0; j < 4; ++j)
                acc[i][j] = fmaf(a[i], bb[j], acc[i][j]);
    }

    bf16* wb = wp + (size_t)b * CH * CH;
    float bvl[4];
    #pragma unroll
    for (int j = 0; j < 4; ++j) bvl[j] = bv[h * HDIM + te + j];

    #pragma unroll
    for (int i = 0; i < 4; ++i) {
        float pi = 0.f;
        #pragma unroll
        for (int j = 0; j < 4; ++j) {
            const bf16 wv16 = (bf16)acc[i][j];
            wb[(size_t)(o0 + to + i) * CH + h * HDIM + te + j] = wv16;
            pi = fmaf((float)wv16, bvl[j], pi);
        }
        // reduce pi over the 16 tx-lanes (same wave: lanes ty*16 .. ty*16+15)
        pi += __shfl_xor(pi, 1);
        pi += __shfl_xor(pi, 2);
        pi += __shfl_xor(pi, 4);
        pi += __shfl_xor(pi, 8);
        if (tx == 0)
            bias2p[((size_t)(b * 8 + h)) * CH + o0 + to + i] = pi;
    }
}

// ---------------------------------------------------------------------------
// Generic 128x128 GEMM, K=512, ring pipeline. Cb -> bf16 scalar epilogue;
// else fp32 via LDS-bounce with bias = bias1[m] + sum_h bias2p[b][h][m].
// ---------------------------------------------------------------------------
__global__ __launch_bounds__(256) void gemm128_kernel(
    const bf16* __restrict__ A, const bf16* __restrict__ Bt,
    const float* __restrict__ bias1, const float* __restrict__ bias2p,
    float* __restrict__ Cf, bf16* __restrict__ Cb,
    int ncols, int c_rows, size_t a_bstride, size_t bt_bstride)
{
    const int nwg  = gridDim.x * gridDim.y;
    const int orig = blockIdx.x + gridDim.x * blockIdx.y;
    const int wg   = (orig & 7) * (nwg >> 3) + (orig >> 3);
    const int by   = wg % gridDim.y;
    const int bx   = wg / gridDim.y;

    const int b  = blockIdx.z;
    const int m0 = by * 128;
    const int n0 = bx * 128;
    const bf16* Ap = A  + (size_t)b * a_bstride;
    const bf16* Bp = Bt + (size_t)b * bt_bstride;

    __shared__ bf16 smem[3 * 8192];

    const int t    = threadIdx.x;
    const int lane = t & 63;
    const int wave = t >> 6;
    const int wr   = wave >> 1, wc = wave & 1;

    f32x4 acc[4][4];
    const f32x4 zf = {0.f, 0.f, 0.f, 0.f};
    #pragma unroll
    for (int i = 0; i < 4; ++i)
        #pragma unroll
        for (int j = 0; j < 4; ++j) acc[i][j] = zf;

    auto STAGE = [&](int tile) {
        bf16* buf = smem + (tile % 3) * 8192;
        const int k0 = tile * 32;
        #pragma unroll
        for (int i = 0; i < 2; ++i) {
            const int c   = t + 256 * i;
            const int row = c >> 2;
            const int kb  = ((c & 3) ^ ((row >> 1) & 3)) * 8;
            __builtin_amdgcn_global_load_lds(
                (const AS1 void*)(Ap + (size_t)(m0 + row) * KDEPTH + k0 + kb),
                (AS3 void*)(buf + c * 8), 16, 0, 0);
            __builtin_amdgcn_global_load_lds(
                (const AS1 void*)(Bp + (size_t)(n0 + row) * KDEPTH + k0 + kb),
                (AS3 void*)(buf + 4096 + c * 8), 16, 0, 0);
        }
    };

    auto COMPUTE = [&](int bufi) {
        const bf16* AsP = smem + bufi * 8192;
        const bf16* BsP = AsP + 4096;
        bf16x8 af[4], bfv[4];
        #pragma unroll
        for (int i = 0; i < 4; ++i) {
            const int ar = wr * 64 + i * 16 + (lane & 15);
            const int ja = (lane >> 4) ^ ((ar >> 1) & 3);
            af[i]  = *(const bf16x8*)(AsP + ar * 32 + ja * 8);
            const int br = wc * 64 + i * 16 + (lane & 15);
            const int jb = (lane >> 4) ^ ((br >> 1) & 3);
            bfv[i] = *(const bf16x8*)(BsP + br * 32 + jb * 8);
        }
        __builtin_amdgcn_s_setprio(1);
        #pragma unroll
        for (int i = 0; i < 4; ++i)
            #pragma unroll
            for (int j = 0; j < 4; ++j)
                acc[i][j] = __builtin_amdgcn_mfma_f32_16x16x32_bf16(
                    af[i], bfv[j], acc[i][j], 0, 0, 0);
        __builtin_amdgcn_s_setprio(0);
    };

    STAGE(0); STAGE(1);
    asm volatile("s_waitcnt vmcnt(4)" ::: "memory");
    asm volatile("s_barrier" ::: "memory");

    int cur = 0;
    for (int kt = 0; kt < 14; ++kt) {
        STAGE(kt + 2);
        COMPUTE(cur);
        __builtin_amdgcn_sched_barrier(0);
        asm volatile("s_waitcnt vmcnt(4)" ::: "memory");
        asm volatile("s_barrier" ::: "memory");
        cur = (cur + 1) % 3;
    }
    COMPUTE(cur);
    __builtin_amdgcn_sched_barrier(0);
    asm volatile("s_waitcnt vmcnt(0)" ::: "memory");
    asm volatile("s_barrier" ::: "memory");
    cur = (cur + 1) % 3;
    COMPUTE(cur);
    __syncthreads();

    if (Cb) {
        #pragma unroll
        for (int i = 0; i < 4; ++i) {
            const int mb = m0 + wr * 64 + i * 16 + (lane >> 4) * 4;
            #pragma unroll
            for (int r = 0; r < 4; ++r) {
                const int m  = mb + r;
                #pragma unroll
                for (int j = 0; j < 4; ++j) {
                    const int n = n0 + wc * 64 + j * 16 + (lane & 15);
                    Cb[(size_t)b * c_rows * ncols + (size_t)m * ncols + n] =
                        (bf16)acc[i][j][r];
                }
            }
        }
    } else {
        float* ct = (float*)smem;
        float* Cp = Cf + (size_t)b * c_rows * ncols;
        #pragma unroll
        for (int p = 0; p < 2; ++p) {
            if (wc == p) {
                #pragma unroll
                for (int i = 0; i < 4; ++i) {
                    const int ml = wr * 64 + i * 16 + (lane >> 4) * 4;
                    #pragma unroll
                    for (int r = 0; r < 4; ++r) {
                        const int m = m0 + ml + r;
                        float bvv = bias1 ? bias1[m] : 0.f;
                        if (bias2p) {
                            #pragma unroll
                            for (int h = 0; h < 8; ++h)
                                bvv += bias2p[((size_t)(b * 8 + h)) * CH + m];
                        }
                        #pragma unroll
                        for (int j = 0; j < 4; ++j) {
                            const int n = j * 16 + (lane & 15);
                            ct[(ml + r) * 64 + n] = acc[i][j][r] + bvv;
                        }
                    }
                }
            }
            __syncthreads();
            #pragma unroll
            for (int ii = 0; ii < 8; ++ii) {
                const int c   = t + 256 * ii;
                const int row = c >> 4;
                const int seg = c & 15;
                const float4 v = *(const float4*)(ct + row * 64 + seg * 4);
                *(float4*)(Cp + (size_t)(m0 + row) * ncols + n0 + p * 64 + seg * 4) = v;
            }
            __syncthreads();
        }
    }
}

// ---------------------------------------------------------------------------
extern "C" void kernel_launch(void* const* d_in, const int* in_sizes, int n_in,
                              void* d_out, int out_size, void* d_ws, size_t ws_size,
                              hipStream_t stream)
{
    (void)in_sizes; (void)n_in; (void)out_size;
    const float* x      = (const float*)d_in[0];
    const float* qkv_w  = (const float*)d_in[1];
    const float* qkv_b  = (const float*)d_in[2];
    const float* proj_w = (const float*)d_in[3];
    const float* proj_b = (const float*)d_in[4];

    float* out       = (float*)d_out;
    float* attn_mean = out + (size_t)BATCH * CH * NPIX;

    const size_t xt_bytes   = (size_t)BATCH * NPIX * CH * 2;            //  32 MiB
    const size_t part_bytes = (size_t)BATCH * HEADS * NSPLIT * HDIM * HDIM * 2; // 16 MiB
    const size_t wq_bytes   = (size_t)OC3 * KDEPTH * 2;                 // 1.5 MiB
    const size_t attn_bytes = (size_t)BATCH * HEADS * HDIM * HDIM * 4;  //   1 MiB
    const size_t wp_bytes   = (size_t)BATCH * CH * CH * 2;              //   4 MiB
    const size_t wpp_bytes  = (size_t)BATCH * CH * CH * 2;              //   4 MiB
    const size_t wvt_bytes  = (size_t)CH * CH * 2;                      // 0.5 MiB
    const size_t b2p_bytes  = (size_t)BATCH * HEADS * CH * 4;           // 128 KiB
    const size_t need = xt_bytes + part_bytes + wq_bytes + attn_bytes +
                        wp_bytes + wpp_bytes + wvt_bytes + b2p_bytes;
    if (ws_size < need) {
        fprintf(stderr, "[kernel_launch] ws_size=%zu < need=%zu — abort\n", ws_size, need);
        fflush(stderr);
        return;
    }

    char* p = (char*)d_ws;
    bf16*  xt     = (bf16*)p;             p += xt_bytes;
    bf16*  part   = (bf16*)p;             p += part_bytes;
    bf16*  wq_b   = (bf16*)p;             p += wq_bytes;
    float* attn   = (float*)p;            p += attn_bytes;
    bf16*  wprime = (bf16*)p;             p += wp_bytes;
    bf16*  wpp    = (bf16*)p;             p += wpp_bytes;
    bf16*  wvt    = (bf16*)p;             p += wvt_bytes;
    float* bias2p = (float*)p;

    // 0) merged prep: weight convert + Wv^T + x transpose
    prep_kernel<<<dim3(NCONV + NWVT + NTRP), 256, 0, stream>>>(
        qkv_w, x, wq_b, wvt, xt);

    // 1) Fused Q/K GEMM + QK^T partial -> part (bf16)
    gemm_qks_kernel<<<dim3(NPIX / 128, HEADS, BATCH), 256, 0, stream>>>(
        wq_b, xt, qkv_b, part);

    // 2) reduce partials + softmax (all heads) + head-mean (output 1)
    qk_reduce_softmax_mean_kernel<<<dim3(8, BATCH), 256, 0, stream>>>(
        part, attn, attn_mean);

    // 3) W' = proj_w · blockdiag(attn)  +  per-head bias2 partials
    wprime_kernel<<<dim3(CH / 64, HEADS, BATCH), 256, 0, stream>>>(
        proj_w, attn, qkv_b + 2 * CH, wprime, bias2p);

    // 4) W'' = W' · Wv (bf16, no bias)
    gemm128_kernel<<<dim3(CH / 128, CH / 128, BATCH), 256, 0, stream>>>(
        wprime, wvt, nullptr, nullptr, nullptr, wpp, CH, CH, (size_t)CH * CH, 0);

    // 5) out = W''_b · x + (proj_b + sum_h bias2p)  (fp32 coalesced epilogue)
    gemm128_kernel<<<dim3(NPIX / 128, CH / 128, BATCH), 256, 0, stream>>>(
        wpp, xt, proj_b, bias2p, out, nullptr, NPIX, CH, (size_t)CH * CH,
        (size_t)NPIX * KDEPTH);
}

// Round 23
// 134.409 us; speedup vs baseline: 1.0403x; 1.0403x over previous
//
#include <hip/hip_runtime.h>
#include <cstdio>
#include <cstdint>

// Problem constants
#define BATCH 8
#define CH    512
#define OC3   1536      // 3*CH
#define NPIX  4096      // 64*64
#define HEADS 8
#define HDIM  64
#define KDEPTH 512
#define SCALE 0.125f    // 64^-0.5
#define NSPLIT 32       // S-partials per (b,h): one per 128-n window

typedef __bf16 bf16;
typedef __bf16 bf16x4 __attribute__((ext_vector_type(4)));
typedef __bf16 bf16x8 __attribute__((ext_vector_type(8)));
typedef float  f32x4  __attribute__((ext_vector_type(4)));

#define AS1 __attribute__((address_space(1)))
#define AS3 __attribute__((address_space(3)))

#define NCONV ((OC3 * KDEPTH) / 256)   // 3072 convert blocks
#define NWVT  64                       // wvt tiles
#define NTRP  (64 * 8 * BATCH)         // 4096 transpose tiles

// ---------------------------------------------------------------------------
// Merged prep: [0,3072) flat convert qkv_w->bf16; [3072,3136) Wv^T tiles;
// [3136,7232) x -> xt transpose tiles. One dispatch, three independent jobs.
// ---------------------------------------------------------------------------
__global__ __launch_bounds__(256) void prep_kernel(
    const float* __restrict__ qkv_w, const float* __restrict__ x,
    bf16* __restrict__ wq_b, bf16* __restrict__ wvt, bf16* __restrict__ xt)
{
    const int bid = blockIdx.x;
    const int t = threadIdx.x;
    __shared__ float shbuf[64 * 68];

    if (bid < NCONV) {
        const int i = bid * 256 + t;
        wq_b[i] = (bf16)qkv_w[i];
        return;
    }
    if (bid < NCONV + NWVT) {
        // Wv^T tile, stride-68 LDS
        const int tb = bid - NCONV;
        const int c0 = (tb & 7) * 64;
        const int d0 = (tb >> 3) * 64;
        const float* wv = qkv_w + (size_t)2 * CH * KDEPTH;
        #pragma unroll
        for (int i = 0; i < 4; ++i) {
            const int lin = t + 256 * i;
            const int row = lin >> 4;
            const int c4  = (lin & 15) * 4;
            const float4 v = *(const float4*)(wv + (size_t)(d0 + row) * CH + c0 + c4);
            shbuf[row * 68 + c4 + 0] = v.x; shbuf[row * 68 + c4 + 1] = v.y;
            shbuf[row * 68 + c4 + 2] = v.z; shbuf[row * 68 + c4 + 3] = v.w;
        }
        __syncthreads();
        #pragma unroll
        for (int i = 0; i < 2; ++i) {
            const int lin  = t + 256 * i;
            const int crow = lin >> 3;
            const int d8   = (lin & 7) * 8;
            bf16x8 v;
            #pragma unroll
            for (int j = 0; j < 8; ++j) v[j] = (bf16)shbuf[(d8 + j) * 68 + crow];
            *(bf16x8*)(wvt + (size_t)(c0 + crow) * CH + d0 + d8) = v;
        }
        return;
    }
    // x transpose tile, stride-65 LDS
    {
        const int tid = bid - NCONV - NWVT;       // 0..4095
        const int b  = tid >> 9;
        const int rem = tid & 511;
        const int n0 = (rem & 63) * 64;
        const int c0 = (rem >> 6) * 64;
        const float* xp = x + (size_t)b * CH * NPIX;

        #pragma unroll
        for (int i = 0; i < 4; ++i) {
            const int lin = t + 256 * i;
            const int r   = lin >> 4;
            const int c4  = (lin & 15) * 4;
            const float4 v = *(const float4*)(xp + (size_t)(c0 + r) * 4096 + n0 + c4);
            shbuf[r * 65 + c4 + 0] = v.x; shbuf[r * 65 + c4 + 1] = v.y;
            shbuf[r * 65 + c4 + 2] = v.z; shbuf[r * 65 + c4 + 3] = v.w;
        }
        __syncthreads();

        bf16* op = xt + (size_t)b * NPIX * CH;
        #pragma unroll
        for (int i = 0; i < 2; ++i) {
            const int lin = t + 256 * i;
            const int n   = lin >> 3;
            const int c8  = (lin & 7) * 8;
            bf16x8 v;
            #pragma unroll
            for (int jj = 0; jj < 8; ++jj) v[jj] = (bf16)shbuf[(c8 + jj) * 65 + n];
            *(bf16x8*)(op + (size_t)(n0 + n) * CH + c0 + c8) = v;
        }
    }
}

// ---------------------------------------------------------------------------
// Fused Q/K GEMM + QK^T partial (R18-proven). Block (nwin=bx, head=by, b):
// tile = [Q_head;K_head] x 128 n, ring pipeline, counted vmcnt(4),
// LDS bounce -> 16 S-MFMA -> part[bh][nwin] (bf16).
// ---------------------------------------------------------------------------
__global__ __launch_bounds__(256) void gemm_qks_kernel(
    const bf16* __restrict__ A, const bf16* __restrict__ Bt,
    const float* __restrict__ qkv_b, bf16* __restrict__ part)
{
    const int nwg  = gridDim.x * gridDim.y;          // 256
    const int orig = blockIdx.x + gridDim.x * blockIdx.y;
    const int wg   = (orig & 7) * (nwg >> 3) + (orig >> 3);
    const int head = wg % gridDim.y;
    const int bx   = wg / gridDim.y;

    const int b  = blockIdx.z;
    const int n0 = bx * 128;
    const bf16* Bp = Bt + (size_t)b * NPIX * KDEPTH;

    __shared__ bf16 smem[3 * 8192];   // ring (48 KB); epilogue reuses 32 KB

    const int t    = threadIdx.x;
    const int lane = t & 63;
    const int wave = t >> 6;
    const int wr   = wave >> 1, wc = wave & 1;

    f32x4 acc[4][4];
    const f32x4 zf = {0.f, 0.f, 0.f, 0.f};
    #pragma unroll
    for (int i = 0; i < 4; ++i)
        #pragma unroll
        for (int j = 0; j < 4; ++j) acc[i][j] = zf;

    auto STAGE = [&](int tile) {
        bf16* buf = smem + (tile % 3) * 8192;
        const int k0 = tile * 32;
        #pragma unroll
        for (int i = 0; i < 2; ++i) {
            const int c   = t + 256 * i;
            const int lr  = c >> 2;          // LDS row 0..127
            const int kb  = ((c & 3) ^ ((lr >> 1) & 3)) * 8;
            const int src = (lr < 64) ? (head * HDIM + lr)
                                      : (CH + head * HDIM + (lr - 64));
            __builtin_amdgcn_global_load_lds(
                (const AS1 void*)(A + (size_t)src * KDEPTH + k0 + kb),
                (AS3 void*)(buf + c * 8), 16, 0, 0);
            __builtin_amdgcn_global_load_lds(
                (const AS1 void*)(Bp + (size_t)(n0 + lr) * KDEPTH + k0 + kb),
                (AS3 void*)(buf + 4096 + c * 8), 16, 0, 0);
        }
    };

    auto COMPUTE = [&](int bufi) {
        const bf16* AsP = smem + bufi * 8192;
        const bf16* BsP = AsP + 4096;
        bf16x8 af[4], bfv[4];
        #pragma unroll
        for (int i = 0; i < 4; ++i) {
            const int ar = wr * 64 + i * 16 + (lane & 15);
            const int ja = (lane >> 4) ^ ((ar >> 1) & 3);
            af[i]  = *(const bf16x8*)(AsP + ar * 32 + ja * 8);
            const int br = wc * 64 + i * 16 + (lane & 15);
            const int jb = (lane >> 4) ^ ((br >> 1) & 3);
            bfv[i] = *(const bf16x8*)(BsP + br * 32 + jb * 8);
        }
        __builtin_amdgcn_s_setprio(1);
        #pragma unroll
        for (int i = 0; i < 4; ++i)
            #pragma unroll
            for (int j = 0; j < 4; ++j)
                acc[i][j] = __builtin_amdgcn_mfma_f32_16x16x32_bf16(
                    af[i], bfv[j], acc[i][j], 0, 0, 0);
        __builtin_amdgcn_s_setprio(0);
    };

    STAGE(0); STAGE(1);
    asm volatile("s_waitcnt vmcnt(4)" ::: "memory");
    asm volatile("s_barrier" ::: "memory");

    int cur = 0;
    for (int kt = 0; kt < 14; ++kt) {
        STAGE(kt + 2);
        COMPUTE(cur);
        __builtin_amdgcn_sched_barrier(0);
        asm volatile("s_waitcnt vmcnt(4)" ::: "memory");
        asm volatile("s_barrier" ::: "memory");
        cur = (cur + 1) % 3;
    }
    COMPUTE(cur);
    __builtin_amdgcn_sched_barrier(0);
    asm volatile("s_waitcnt vmcnt(0)" ::: "memory");
    asm volatile("s_barrier" ::: "memory");
    cur = (cur + 1) % 3;
    COMPUTE(cur);
    __syncthreads();

    // Bounce: acc (+bias) -> ct[128 rows][128 n] bf16, chunk-slot ^ (row&15)
    bf16* ct = smem;
    #pragma unroll
    for (int i = 0; i < 4; ++i) {
        const int mlb = wr * 64 + i * 16 + (lane >> 4) * 4;
        #pragma unroll
        for (int r = 0; r < 4; ++r) {
            const int row = mlb + r;
            const int bsrc = (row < 64) ? (head * HDIM + row)
                                        : (CH + head * HDIM + (row - 64));
            const float bv = qkv_b[bsrc];
            #pragma unroll
            for (int j = 0; j < 4; ++j) {
                const int n = wc * 64 + j * 16 + (lane & 15);
                ct[row * 128 + (((n >> 3) ^ (row & 15)) * 8) + (n & 7)] =
                    (bf16)(acc[i][j][r] + bv);
            }
        }
    }
    __syncthreads();

    // S-partial: wave w -> e-range w*16..+16. 4 ksteps of 32 n.
    f32x4 sacc[4];
    #pragma unroll
    for (int df = 0; df < 4; ++df) sacc[df] = zf;
    #pragma unroll
    for (int ks = 0; ks < 4; ++ks) {
        const int slot8 = ((ks * 4 + (lane >> 4)) ^ (lane & 15)) * 8;
        const bf16x8 kf = *(const bf16x8*)(ct + (64 + wave * 16 + (lane & 15)) * 128 + slot8);
        #pragma unroll
        for (int df = 0; df < 4; ++df) {
            const bf16x8 qf = *(const bf16x8*)(ct + (df * 16 + (lane & 15)) * 128 + slot8);
            sacc[df] = __builtin_amdgcn_mfma_f32_16x16x32_bf16(qf, kf, sacc[df], 0, 0, 0);
        }
    }

    bf16* pp = part + (((size_t)(b * 8 + head) * NSPLIT + bx) * 64) * 64;
    #pragma unroll
    for (int df = 0; df < 4; ++df)
        #pragma unroll
        for (int r = 0; r < 4; ++r)
            pp[(size_t)(df * 16 + (lane >> 4) * 4 + r) * 64 + wave * 16 + (lane & 15)]
                = (bf16)sacc[df][r];
}

// ---------------------------------------------------------------------------
// Reduce 32 bf16 partials + row softmax -> attn[bh][d][e] fp32. grid (8, 64).
// Block (rg, bh): rows rg*8..+8; 32 threads per row, paired e (2le, 2le+1).
// ---------------------------------------------------------------------------
__global__ __launch_bounds__(256) void qk_reduce_softmax_kernel(
    const bf16* __restrict__ part, float* __restrict__ attn)
{
    const int rg = blockIdx.x, bh = blockIdx.y;
    const int t  = threadIdx.x;
    const int row = rg * 8 + (t >> 5);
    const int le  = t & 31;

    const bf16* pb = part + (size_t)bh * NSPLIT * 4096 + row * 64 + 2 * le;
    float v0 = 0.f, v1 = 0.f;
    #pragma unroll 8
    for (int s = 0; s < NSPLIT; ++s) {
        v0 += (float)pb[(size_t)s * 4096];
        v1 += (float)pb[(size_t)s * 4096 + 1];
    }

    float m = fmaxf(v0, v1);
    m = fmaxf(m, __shfl_xor(m, 1));
    m = fmaxf(m, __shfl_xor(m, 2));
    m = fmaxf(m, __shfl_xor(m, 4));
    m = fmaxf(m, __shfl_xor(m, 8));
    m = fmaxf(m, __shfl_xor(m, 16));

    v0 = __expf((v0 - m) * SCALE);
    v1 = __expf((v1 - m) * SCALE);
    float sum = v0 + v1;
    sum += __shfl_xor(sum, 1);
    sum += __shfl_xor(sum, 2);
    sum += __shfl_xor(sum, 4);
    sum += __shfl_xor(sum, 8);
    sum += __shfl_xor(sum, 16);
    const float inv = 1.f / sum;

    float* arow = attn + ((size_t)bh * 64 + row) * 64;
    float2 o; o.x = v0 * inv; o.y = v1 * inv;
    *(float2*)(arow + 2 * le) = o;
}

// ---------------------------------------------------------------------------
// attn_mean[b][d][e] = mean_h attn[b][h][d][e]
// ---------------------------------------------------------------------------
__global__ __launch_bounds__(256) void attn_mean_kernel(
    const float* __restrict__ attn, float* __restrict__ om)
{
    const int idx = blockIdx.x * 256 + threadIdx.x;
    const int b = idx >> 12, de = idx & 4095;
    float s = 0.f;
    #pragma unroll
    for (int h = 0; h < 8; ++h)
        s += attn[(((size_t)b * 8 + h) << 12) + de];
    om[idx] = s * 0.125f;
}

// ---------------------------------------------------------------------------
// W'[b][o][h*64+e] = sum_d proj_w[o][h*64+d] * attn[b,h,d,e]   (fp32 -> bf16)
// ---------------------------------------------------------------------------
__global__ __launch_bounds__(256) void wprime_kernel(
    const float* __restrict__ proj_w, const float* __restrict__ attn,
    bf16* __restrict__ wp)
{
    const int o0 = blockIdx.x * 64;
    const int h  = blockIdx.y;
    const int b  = blockIdx.z;

    __shared__ float ws[64][65];
    __shared__ float as_[64][65];

    const int t = threadIdx.x;
    #pragma unroll
    for (int i = 0; i < 4; ++i) {
        const int lin = t + 256 * i;
        const int r   = lin >> 4;
        const int c4  = (lin & 15) * 4;
        const float4 wv = *(const float4*)(proj_w + (size_t)(o0 + r) * CH + h * HDIM + c4);
        ws[r][c4 + 0] = wv.x; ws[r][c4 + 1] = wv.y;
        ws[r][c4 + 2] = wv.z; ws[r][c4 + 3] = wv.w;
        const float4 av = *(const float4*)(attn + (((size_t)(b * 8 + h) * 64) + r) * 64 + c4);
        as_[r][c4 + 0] = av.x; as_[r][c4 + 1] = av.y;
        as_[r][c4 + 2] = av.z; as_[r][c4 + 3] = av.w;
    }
    __syncthreads();

    const int tx = t & 15, ty = t >> 4;
    const int to = ty * 4, te = tx * 4;
    float acc[4][4] = {};
    for (int d = 0; d < 64; ++d) {
        float a[4], bb[4];
        #pragma unroll
        for (int i = 0; i < 4; ++i) a[i]  = ws[to + i][d];
        #pragma unroll
        for (int j = 0; j < 4; ++j) bb[j] = as_[d][te + j];
        #pragma unroll
        for (int i = 0; i < 4; ++i)
            #pragma unroll
            for (int j = 0; j < 4; ++j)
                acc[i][j] = fmaf(a[i], bb[j], acc[i][j]);
    }

    bf16* wb = wp + (size_t)b * CH * CH;
    #pragma unroll
    for (int i = 0; i < 4; ++i)
        #pragma unroll
        for (int j = 0; j < 4; ++j)
            wb[(size_t)(o0 + to + i) * CH + h * HDIM + te + j] = (bf16)acc[i][j];
}

// ---------------------------------------------------------------------------
// bias2[b][o] = sum_d W'[b][o][d] * bv[d] + pb[o]
// ---------------------------------------------------------------------------
__global__ __launch_bounds__(256) void bias2_kernel(
    const bf16* __restrict__ wp, const float* __restrict__ bv,
    const float* __restrict__ pb, float* __restrict__ bias2)
{
    const int idx = blockIdx.x * 256 + threadIdx.x;   // < 4096
    const int b = idx >> 9, o = idx & 511;
    const bf16* wr = wp + ((size_t)b * CH + o) * CH;
    float s = 0.f;
    for (int d = 0; d < 512; ++d) s += (float)wr[d] * bv[d];
    bias2[idx] = s + pb[o];
}

// ---------------------------------------------------------------------------
// Generic 128x128 GEMM, K=512, ring pipeline. Cb -> bf16 scalar epilogue;
// else fp32 via LDS-bounce. XCD swizzle. bias[b*bstride+m].
// ---------------------------------------------------------------------------
__global__ __launch_bounds__(256) void gemm128_kernel(
    const bf16* __restrict__ A, const bf16* __restrict__ Bt,
    const float* __restrict__ bias, size_t bias_bstride,
    float* __restrict__ Cf, bf16* __restrict__ Cb,
    int ncols, int c_rows, size_t a_bstride, size_t bt_bstride)
{
    const int nwg  = gridDim.x * gridDim.y;
    const int orig = blockIdx.x + gridDim.x * blockIdx.y;
    const int wg   = (orig & 7) * (nwg >> 3) + (orig >> 3);
    const int by   = wg % gridDim.y;
    const int bx   = wg / gridDim.y;

    const int b  = blockIdx.z;
    const int m0 = by * 128;
    const int n0 = bx * 128;
    const bf16* Ap = A  + (size_t)b * a_bstride;
    const bf16* Bp = Bt + (size_t)b * bt_bstride;

    __shared__ bf16 smem[3 * 8192];

    const int t    = threadIdx.x;
    const int lane = t & 63;
    const int wave = t >> 6;
    const int wr   = wave >> 1, wc = wave & 1;

    f32x4 acc[4][4];
    const f32x4 zf = {0.f, 0.f, 0.f, 0.f};
    #pragma unroll
    for (int i = 0; i < 4; ++i)
        #pragma unroll
        for (int j = 0; j < 4; ++j) acc[i][j] = zf;

    auto STAGE = [&](int tile) {
        bf16* buf = smem + (tile % 3) * 8192;
        const int k0 = tile * 32;
        #pragma unroll
        for (int i = 0; i < 2; ++i) {
            const int c   = t + 256 * i;
            const int row = c >> 2;
            const int kb  = ((c & 3) ^ ((row >> 1) & 3)) * 8;
            __builtin_amdgcn_global_load_lds(
                (const AS1 void*)(Ap + (size_t)(m0 + row) * KDEPTH + k0 + kb),
                (AS3 void*)(buf + c * 8), 16, 0, 0);
            __builtin_amdgcn_global_load_lds(
                (const AS1 void*)(Bp + (size_t)(n0 + row) * KDEPTH + k0 + kb),
                (AS3 void*)(buf + 4096 + c * 8), 16, 0, 0);
        }
    };

    auto COMPUTE = [&](int bufi) {
        const bf16* AsP = smem + bufi * 8192;
        const bf16* BsP = AsP + 4096;
        bf16x8 af[4], bfv[4];
        #pragma unroll
        for (int i = 0; i < 4; ++i) {
            const int ar = wr * 64 + i * 16 + (lane & 15);
            const int ja = (lane >> 4) ^ ((ar >> 1) & 3);
            af[i]  = *(const bf16x8*)(AsP + ar * 32 + ja * 8);
            const int br = wc * 64 + i * 16 + (lane & 15);
            const int jb = (lane >> 4) ^ ((br >> 1) & 3);
            bfv[i] = *(const bf16x8*)(BsP + br * 32 + jb * 8);
        }
        __builtin_amdgcn_s_setprio(1);
        #pragma unroll
        for (int i = 0; i < 4; ++i)
            #pragma unroll
            for (int j = 0; j < 4; ++j)
                acc[i][j] = __builtin_amdgcn_mfma_f32_16x16x32_bf16(
                    af[i], bfv[j], acc[i][j], 0, 0, 0);
        __builtin_amdgcn_s_setprio(0);
    };

    STAGE(0); STAGE(1);
    asm volatile("s_waitcnt vmcnt(4)" ::: "memory");
    asm volatile("s_barrier" ::: "memory");

    int cur = 0;
    for (int kt = 0; kt < 14; ++kt) {
        STAGE(kt + 2);
        COMPUTE(cur);
        __builtin_amdgcn_sched_barrier(0);
        asm volatile("s_waitcnt vmcnt(4)" ::: "memory");
        asm volatile("s_barrier" ::: "memory");
        cur = (cur + 1) % 3;
    }
    COMPUTE(cur);
    __builtin_amdgcn_sched_barrier(0);
    asm volatile("s_waitcnt vmcnt(0)" ::: "memory");
    asm volatile("s_barrier" ::: "memory");
    cur = (cur + 1) % 3;
    COMPUTE(cur);
    __syncthreads();

    if (Cb) {
        #pragma unroll
        for (int i = 0; i < 4; ++i) {
            const int mb = m0 + wr * 64 + i * 16 + (lane >> 4) * 4;
            #pragma unroll
            for (int r = 0; r < 4; ++r) {
                const int m  = mb + r;
                const float bv = bias ? bias[b * bias_bstride + m] : 0.f;
                #pragma unroll
                for (int j = 0; j < 4; ++j) {
                    const int n = n0 + wc * 64 + j * 16 + (lane & 15);
                    Cb[(size_t)b * c_rows * ncols + (size_t)m * ncols + n] =
                        (bf16)(acc[i][j][r] + bv);
                }
            }
        }
    } else {
        float* ct = (float*)smem;
        float* Cp = Cf + (size_t)b * c_rows * ncols;
        #pragma unroll
        for (int p = 0; p < 2; ++p) {
            if (wc == p) {
                #pragma unroll
                for (int i = 0; i < 4; ++i) {
                    const int ml = wr * 64 + i * 16 + (lane >> 4) * 4;
                    #pragma unroll
                    for (int r = 0; r < 4; ++r) {
                        const float bv = bias ? bias[b * bias_bstride + m0 + ml + r] : 0.f;
                        #pragma unroll
                        for (int j = 0; j < 4; ++j) {
                            const int n = j * 16 + (lane & 15);
                            ct[(ml + r) * 64 + n] = acc[i][j][r] + bv;
                        }
                    }
                }
            }
            __syncthreads();
            #pragma unroll
            for (int ii = 0; ii < 8; ++ii) {
                const int c   = t + 256 * ii;
                const int row = c >> 4;
                const int seg = c & 15;
                const float4 v = *(const float4*)(ct + row * 64 + seg * 4);
                *(float4*)(Cp + (size_t)(m0 + row) * ncols + n0 + p * 64 + seg * 4) = v;
            }
            __syncthreads();
        }
    }
}

// ---------------------------------------------------------------------------
extern "C" void kernel_launch(void* const* d_in, const int* in_sizes, int n_in,
                              void* d_out, int out_size, void* d_ws, size_t ws_size,
                              hipStream_t stream)
{
    (void)in_sizes; (void)n_in; (void)out_size;
    const float* x      = (const float*)d_in[0];
    const float* qkv_w  = (const float*)d_in[1];
    const float* qkv_b  = (const float*)d_in[2];
    const float* proj_w = (const float*)d_in[3];
    const float* proj_b = (const float*)d_in[4];

    float* out       = (float*)d_out;
    float* attn_mean = out + (size_t)BATCH * CH * NPIX;

    const size_t xt_bytes   = (size_t)BATCH * NPIX * CH * 2;            //  32 MiB
    const size_t part_bytes = (size_t)BATCH * HEADS * NSPLIT * HDIM * HDIM * 2; // 16 MiB
    const size_t wq_bytes   = (size_t)OC3 * KDEPTH * 2;                 // 1.5 MiB
    const size_t attn_bytes = (size_t)BATCH * HEADS * HDIM * HDIM * 4;  //   1 MiB
    const size_t wp_bytes   = (size_t)BATCH * CH * CH * 2;              //   4 MiB
    const size_t wpp_bytes  = (size_t)BATCH * CH * CH * 2;              //   4 MiB
    const size_t wvt_bytes  = (size_t)CH * CH * 2;                      // 0.5 MiB
    const size_t b2_bytes   = (size_t)BATCH * CH * 4;                   //  16 KiB
    const size_t need = xt_bytes + part_bytes + wq_bytes + attn_bytes +
                        wp_bytes + wpp_bytes + wvt_bytes + b2_bytes;
    if (ws_size < need) {
        fprintf(stderr, "[kernel_launch] ws_size=%zu < need=%zu — abort\n", ws_size, need);
        fflush(stderr);
        return;
    }

    char* p = (char*)d_ws;
    bf16*  xt     = (bf16*)p;             p += xt_bytes;
    bf16*  part   = (bf16*)p;             p += part_bytes;
    bf16*  wq_b   = (bf16*)p;             p += wq_bytes;
    float* attn   = (float*)p;            p += attn_bytes;
    bf16*  wprime = (bf16*)p;             p += wp_bytes;
    bf16*  wpp    = (bf16*)p;             p += wpp_bytes;
    bf16*  wvt    = (bf16*)p;             p += wvt_bytes;
    float* bias2  = (float*)p;

    // 0) merged prep: weight convert + Wv^T + x transpose (one dispatch)
    prep_kernel<<<dim3(NCONV + NWVT + NTRP), 256, 0, stream>>>(
        qkv_w, x, wq_b, wvt, xt);

    // 1) Fused Q/K GEMM + QK^T partial -> part (bf16)
    gemm_qks_kernel<<<dim3(NPIX / 128, HEADS, BATCH), 256, 0, stream>>>(
        wq_b, xt, qkv_b, part);

    // 2) reduce partials + softmax -> attn
    qk_reduce_softmax_kernel<<<dim3(8, BATCH * HEADS), 256, 0, stream>>>(part, attn);

    // 3) attn mean over heads (output 1)
    attn_mean_kernel<<<dim3(BATCH * HDIM * HDIM / 256), 256, 0, stream>>>(attn, attn_mean);

    // 4) W' = proj_w · blockdiag(attn)
    wprime_kernel<<<dim3(CH / 64, HEADS, BATCH), 256, 0, stream>>>(proj_w, attn, wprime);

    // 5) W'' = W' · Wv (bf16) ; bias'' = W'·bv + pb
    gemm128_kernel<<<dim3(CH / 128, CH / 128, BATCH), 256, 0, stream>>>(
        wprime, wvt, nullptr, 0, nullptr, wpp, CH, CH, (size_t)CH * CH, 0);
    bias2_kernel<<<dim3(BATCH * CH / 256), 256, 0, stream>>>(
        wprime, qkv_b + 2 * CH, proj_b, bias2);

    // 6) out = W''_b · x + bias''  (fp32 coalesced epilogue)
    gemm128_kernel<<<dim3(NPIX / 128, CH / 128, BATCH), 256, 0, stream>>>(
        wpp, xt, bias2, CH, out, nullptr, NPIX, CH, (size_t)CH * CH,
        (size_t)NPIX * KDEPTH);
}